// Round 13
// baseline (178.339 us; speedup 1.0000x reference)
//
#include <hip/hip_runtime.h>

typedef short  short8  __attribute__((ext_vector_type(8)));
typedef short  short4v __attribute__((ext_vector_type(4)));
typedef float  float4v __attribute__((ext_vector_type(4)));
typedef int    int4v   __attribute__((ext_vector_type(4)));
typedef int    int2v   __attribute__((ext_vector_type(2)));

#define LOG2E 1.4426950408889634f

static __device__ __forceinline__ short f2bf(float f) {
  unsigned u = __builtin_bit_cast(unsigned, f);
  u = (u + 0x7fffu + ((u >> 16) & 1u)) >> 16;   // RNE
  return (short)u;
}
static __device__ __forceinline__ float bf2f(short s) {
  return __builtin_bit_cast(float, ((unsigned)(unsigned short)s) << 16);
}

typedef __attribute__((address_space(3))) char  as3c;
typedef __attribute__((address_space(1))) char  as1c;
static __device__ __forceinline__ void dma16(const void* g, void* l) {
  __builtin_amdgcn_global_load_lds((const as1c*)g, (as3c*)l, 16, 0, 0);
}

// ---------------------------------------------------------------------------
// Kernel 1: h = x @ w.T  (8192x256, K=256), hi/lo bf16-split MFMA for ~f32
// accuracy. Writes hT bf16 [256][8192] (ws) and hT f32 [256][8192] (d_out,
// transient — consumed by k_scores1; d_out fully rewritten by k_out).
// ---------------------------------------------------------------------------
__global__ __launch_bounds__(256) void k_hgemm(
    const float* __restrict__ x, const float* __restrict__ w,
    short* __restrict__ hT, float* __restrict__ hTf) {
  const int I0   = blockIdx.x * 64;
  const int lane = threadIdx.x & 63;
  const int wn   = threadIdx.x >> 6;       // 4 waves split N (cols)
  const int lrow = lane & 15;
  const int lk8  = (lane >> 4) << 3;

  float4v zero4 = {0.f, 0.f, 0.f, 0.f};
  float4v acc[4][4];
  #pragma unroll
  for (int mi = 0; mi < 4; ++mi)
    #pragma unroll
    for (int ni = 0; ni < 4; ++ni) acc[mi][ni] = zero4;

  for (int k0 = 0; k0 < 256; k0 += 32) {
    short8 ah[4], al[4], bh[4], bl[4];
    #pragma unroll
    for (int mi = 0; mi < 4; ++mi) {
      const float* xp = x + (size_t)(I0 + mi * 16 + lrow) * 256 + k0 + lk8;
      float4v va = *(const float4v*)xp;
      float4v vb = *(const float4v*)(xp + 4);
      #pragma unroll
      for (int e = 0; e < 4; ++e) {
        short h = f2bf(va[e]); ah[mi][e] = h;     al[mi][e]     = f2bf(va[e] - bf2f(h));
        h = f2bf(vb[e]);       ah[mi][4 + e] = h; al[mi][4 + e] = f2bf(vb[e] - bf2f(h));
      }
    }
    #pragma unroll
    for (int ni = 0; ni < 4; ++ni) {
      const float* wp = w + (size_t)(wn * 64 + ni * 16 + lrow) * 256 + k0 + lk8;
      float4v va = *(const float4v*)wp;
      float4v vb = *(const float4v*)(wp + 4);
      #pragma unroll
      for (int e = 0; e < 4; ++e) {
        short h = f2bf(va[e]); bh[ni][e] = h;     bl[ni][e]     = f2bf(va[e] - bf2f(h));
        h = f2bf(vb[e]);       bh[ni][4 + e] = h; bl[ni][4 + e] = f2bf(vb[e] - bf2f(h));
      }
    }
    #pragma unroll
    for (int mi = 0; mi < 4; ++mi)
      #pragma unroll
      for (int ni = 0; ni < 4; ++ni) {
        acc[mi][ni] = __builtin_amdgcn_mfma_f32_16x16x32_bf16(al[mi], bh[ni], acc[mi][ni], 0, 0, 0);
        acc[mi][ni] = __builtin_amdgcn_mfma_f32_16x16x32_bf16(ah[mi], bl[ni], acc[mi][ni], 0, 0, 0);
        acc[mi][ni] = __builtin_amdgcn_mfma_f32_16x16x32_bf16(ah[mi], bh[ni], acc[mi][ni], 0, 0, 0);
      }
  }
  const int r0 = (lane >> 4) << 2;   // C/D: col=lane&15, row=(lane>>4)*4+reg
  #pragma unroll
  for (int mi = 0; mi < 4; ++mi)
    #pragma unroll
    for (int ni = 0; ni < 4; ++ni) {
      const int c   = wn * 64 + ni * 16 + lrow;
      const int row = I0 + mi * 16 + r0;
      float4v v = acc[mi][ni];
      short4v sv;
      #pragma unroll
      for (int r = 0; r < 4; ++r) sv[r] = f2bf(v[r]);
      *(short4v*)(hT + (size_t)c * 8192 + row) = sv;
      *(float4v*)(hTf + (size_t)c * 8192 + row) = v;
    }
}

// ---------------------------------------------------------------------------
// Kernel 2: s1 = h@a1, s2 = h@a2 partials (split-K = 2)
// ---------------------------------------------------------------------------
__global__ __launch_bounds__(256) void k_scores1(
    const float* __restrict__ hTf, const float* __restrict__ a,
    float* __restrict__ t1p, float* __restrict__ t2p) {
  const int i = blockIdx.x * 256 + threadIdx.x;
  const int q = blockIdx.y;
  float s1 = 0.f, s2 = 0.f;
  #pragma unroll 8
  for (int kf = q * 128; kf < q * 128 + 128; ++kf) {
    float hv = hTf[(size_t)kf * 8192 + i];
    s1 = fmaf(hv, a[kf], s1);
    s2 = fmaf(hv, a[256 + kf], s2);
  }
  t1p[q * 8192 + i] = s1;
  t2p[q * 8192 + i] = s2;
}

// ---------------------------------------------------------------------------
// Kernel 3: reduce partials, emit exp2 tables:
//   e1f1[i] = {exp2(t1c), exp2(0.2 t1c)},  ef2[j] = {exp2(t2c), exp2(0.2 t2c)}
// so W = adj ? max(e1*e2, f1*f2) : 1  (exp2 of leaky-relu separable via
// monotonicity — no per-element transcendental in k_gat).
// ---------------------------------------------------------------------------
__global__ __launch_bounds__(256) void k_scores2(
    const float* __restrict__ t1p, const float* __restrict__ t2p,
    float2* __restrict__ e1f1, float2* __restrict__ ef2) {
  const int i = blockIdx.x * 256 + threadIdx.x;
  const float t1 = LOG2E * (t1p[i] + t1p[8192 + i]);
  const float t2 = LOG2E * (t2p[i] + t2p[8192 + i]);
  e1f1[i] = make_float2(exp2f(t1), exp2f(0.2f * t1));
  ef2[i]  = make_float2(exp2f(t2), exp2f(0.2f * t2));
}

// ---------------------------------------------------------------------------
// Kernel 4: fused GAT GEMM — r12's counted-vmcnt schedule at 2 blocks/CU.
// r12 (1 block/CU) left the per-tile phase chain serialized across all 8
// lockstep waves; with 2 co-resident blocks the other block's MFMA covers
// this block's WCOMP/barrier (m114). BK=32, split-K=8: grid (64,8) = 512
// blocks = 2/CU. LDS 63KB/block: Wt[2] 88B rows (22-bank stride -> max
// 2 lanes/bank-group on write AND frag read = free), Hb[2] 64B rows linear
// for DMA with (r>>1)&3 chunk-permutation via pre-swizzled DMA SOURCE
// (fixes the r,r+4,r+8,r+12 4-way alias of a r&3 swizzle), Elds 72B-stride
// groups (WCOMP reads are same-address broadcast, 4 disjoint bank groups).
// Per tile: DMA H(s+1) | 8 frag ds_reads + setprio(1) 16 MFMA setprio(0) |
// WCOMP(s+1) (auto-wait drains adj only) | issue adj(s+2) (clamped, every
// tile -> constant queue) | s_waitcnt vmcnt(2) lgkmcnt(0) + raw s_barrier
// (adj loads stay in flight across the barrier). sched_barrier(0) pins
// each issue group (r11 lesson).
// ---------------------------------------------------------------------------
__global__ __launch_bounds__(512, 4) void k_gat(
    const int* __restrict__ adj, const short* __restrict__ hT,
    const float2* __restrict__ e1f1, const float2* __restrict__ ef2,
    float* __restrict__ Np, float* __restrict__ Zp) {
  __shared__ __align__(16) char Wt[2][11264];   // 128 rows x 88B (32j bf16 + 24B pad)
  __shared__ __align__(16) char Hb[2][16384];   // 256 rows x 64B, linear (DMA)
  __shared__ __align__(16) char Elds[9216];     // 32 tiles x 4 groups x 72B stride

  const int tid = threadIdx.x, lane = tid & 63, wave = tid >> 6;
  const int wm = wave >> 2, wn = wave & 3;
  const int lrow = lane & 15;
  const int I0 = blockIdx.x * 128;
  const int j0 = blockIdx.y * 1024;

  // --- W staging map: thread -> row ar (all 128 rows, 4 thr/row), 8-j chunk
  const int ar = tid >> 2, ac = tid & 3;
  const int* agp = adj + (size_t)(I0 + ar) * 8192 + j0 + ac * 8;
  float e1v, f1v;
  { float2 v = e1f1[I0 + ar]; e1v = v.x; f1v = v.y; }
  const int wwo = ar * 88 + ac * 16;            // single b128 write/tile
  const int ec72 = ac * 72;

  // --- H DMA: wave -> rows wave*32..+31 (2 instrs x 16 rows); lane l ->
  //     row +(l>>2), phys chunk l&3, GLOBAL chunk (l&3)^((l>>3)&3)
  const short* hdma = hT + (size_t)(wave * 32 + (lane >> 2)) * 8192 + j0
                    + (((lane & 3) ^ ((lane >> 3) & 3)) << 3);
  const int hlo = wave * 2048;                  // + q*1024, + buf

  // --- frag-read bases
  const int ardo = (wm * 64 + lrow) * 88 + ((lane >> 4) << 4);  // + mi*1408
  const int brdo = (wn * 64 + lrow) * 64
                 + (((lane >> 4) ^ ((lrow >> 1) & 3)) << 4);    // + ni*1024

  float4v zero4 = {0.f, 0.f, 0.f, 0.f};
  float4v acc[4][4];
  #pragma unroll
  for (int mi = 0; mi < 4; ++mi)
    #pragma unroll
    for (int ni = 0; ni < 4; ++ni) acc[mi][ni] = zero4;
  float zacc = 0.f;
  int4v ga0, ga1;

#define WCOMP(T, DST)                                                         \
  { const char* eb = Elds + (T) * 288 + ec72;                                 \
    const float4v E0 = *(const float4v*)(eb);                                 \
    const float4v E1 = *(const float4v*)(eb + 16);                            \
    const float4v E2 = *(const float4v*)(eb + 32);                            \
    const float4v E3 = *(const float4v*)(eb + 48);                            \
    float w0 = ga0[0] ? fmaxf(e1v * E0[0], f1v * E0[1]) : 1.0f;               \
    float w1 = ga0[1] ? fmaxf(e1v * E0[2], f1v * E0[3]) : 1.0f;               \
    float w2 = ga0[2] ? fmaxf(e1v * E1[0], f1v * E1[1]) : 1.0f;               \
    float w3 = ga0[3] ? fmaxf(e1v * E1[2], f1v * E1[3]) : 1.0f;               \
    float w4 = ga1[0] ? fmaxf(e1v * E2[0], f1v * E2[1]) : 1.0f;               \
    float w5 = ga1[1] ? fmaxf(e1v * E2[2], f1v * E2[3]) : 1.0f;               \
    float w6 = ga1[2] ? fmaxf(e1v * E3[0], f1v * E3[1]) : 1.0f;               \
    float w7 = ga1[3] ? fmaxf(e1v * E3[2], f1v * E3[3]) : 1.0f;               \
    zacc += ((w0 + w1) + (w2 + w3)) + ((w4 + w5) + (w6 + w7));                \
    int4v pw;                                                                 \
    asm("v_cvt_pk_bf16_f32 %0, %1, %2" : "=v"(pw[0]) : "v"(w0), "v"(w1));     \
    asm("v_cvt_pk_bf16_f32 %0, %1, %2" : "=v"(pw[1]) : "v"(w2), "v"(w3));     \
    asm("v_cvt_pk_bf16_f32 %0, %1, %2" : "=v"(pw[2]) : "v"(w4), "v"(w5));     \
    asm("v_cvt_pk_bf16_f32 %0, %1, %2" : "=v"(pw[3]) : "v"(w6), "v"(w7));     \
    *(int4v*)((DST) + wwo) = pw; }

  // --- prologue: Elds fill (72B-stride groups) -> barrier; tile-0 staging
  {
    const int b = tid >> 2;                     // 64B block 0..127
    *(float4v*)(Elds + (b >> 2) * 288 + (b & 3) * 72 + (tid & 3) * 16) =
        *(const float4v*)((const char*)(ef2 + j0) + tid * 16);
  }
  __syncthreads();
  ga0 = __builtin_nontemporal_load((const int4v*)(agp));
  ga1 = __builtin_nontemporal_load((const int4v*)(agp + 4));
  __builtin_amdgcn_sched_barrier(0);            // adj0 first
  dma16(hdma, Hb[0] + hlo);
  dma16(hdma + 131072, Hb[0] + hlo + 1024);     // +16 rows
  __builtin_amdgcn_sched_barrier(0);            // DMAs after adj0
  WCOMP(0, Wt[0]);                              // auto vmcnt drains adj0 only
  ga0 = __builtin_nontemporal_load((const int4v*)(agp + 32));
  ga1 = __builtin_nontemporal_load((const int4v*)(agp + 36));
  __builtin_amdgcn_sched_barrier(0);            // adj1 after DMAs
  asm volatile("s_waitcnt vmcnt(2) lgkmcnt(0)" ::: "memory");
  __builtin_amdgcn_s_barrier();
  __builtin_amdgcn_sched_barrier(0);

  #pragma unroll 2
  for (int s = 0; s < 32; ++s) {
    const int cur = s & 1, nx = cur ^ 1;
    // P1: DMA H(s+1) -> Hb[nx]
    if (s < 31) {
      const int so = (s + 1) * 32;              // shorts
      dma16(hdma + so, Hb[nx] + hlo);
      dma16(hdma + so + 131072, Hb[nx] + hlo + 1024);
    }
    __builtin_amdgcn_sched_barrier(0);          // pin DMA issue point
    // P2: frag reads + 16 MFMA (setprio: 2 blocks/CU -> role diversity)
    short8 af[4], bf[4];
    #pragma unroll
    for (int mi = 0; mi < 4; ++mi) af[mi] = *(const short8*)(Wt[cur] + ardo + mi * 1408);
    #pragma unroll
    for (int ni = 0; ni < 4; ++ni) bf[ni] = *(const short8*)(Hb[cur] + brdo + ni * 1024);
    __builtin_amdgcn_s_setprio(1);
    #pragma unroll
    for (int mi = 0; mi < 4; ++mi)
      #pragma unroll
      for (int ni = 0; ni < 4; ++ni)
        acc[mi][ni] = __builtin_amdgcn_mfma_f32_16x16x32_bf16(af[mi], bf[ni], acc[mi][ni], 0, 0, 0);
    __builtin_amdgcn_s_setprio(0);
    // P3: W-compute(s+1) -> Wt[nx] (auto vmcnt drains adj(s+1) only)
    if (s < 31) WCOMP(s + 1, Wt[nx]);
    // P4: issue adj (every s<31, clamped -> constant vmcnt queue)
    if (s < 31) {
      const int sp = (s + 2 < 32) ? s + 2 : 31;
      ga0 = __builtin_nontemporal_load((const int4v*)(agp + sp * 32));
      ga1 = __builtin_nontemporal_load((const int4v*)(agp + sp * 32 + 4));
    }
    __builtin_amdgcn_sched_barrier(0);          // pin adj issue after DMAs
    // P6: counted drain (DMAs only; adj stays in flight) + raw barrier
    if (s < 31) {
      asm volatile("s_waitcnt vmcnt(2) lgkmcnt(0)" ::: "memory");
      __builtin_amdgcn_s_barrier();
      __builtin_amdgcn_sched_barrier(0);
    }
  }
#undef WCOMP

  // Z reduce: 4 thread-partials per row (alias Elds; all reads done)
  __syncthreads();
  float* zl = (float*)Elds;
  zl[ar * 4 + ac] = zacc;
  __syncthreads();
  if (tid < 128) {
    float z = zl[tid * 4] + zl[tid * 4 + 1] + zl[tid * 4 + 2] + zl[tid * 4 + 3];
    Zp[(size_t)blockIdx.y * 8192 + I0 + tid] = z;
  }

  // N partial store (direct, no atomics)
  float* Npb = Np + (size_t)blockIdx.y * 2097152;
  const int r0 = (lane >> 4) << 2;
  #pragma unroll
  for (int mi = 0; mi < 4; ++mi) {
    const int rowb = I0 + wm * 64 + mi * 16 + r0;
    #pragma unroll
    for (int ni = 0; ni < 4; ++ni) {
      const int col = wn * 64 + ni * 16 + lrow;
      #pragma unroll
      for (int r = 0; r < 4; ++r)
        Npb[(size_t)(rowb + r) * 256 + col] = acc[mi][ni][r];
    }
  }
}

// ---------------------------------------------------------------------------
// Kernel 5: out = elu( (sum_y Np) / (sum_y Zp) )   (8 split-K slabs)
// ---------------------------------------------------------------------------
__global__ __launch_bounds__(256) void k_out(
    const float* __restrict__ Np, const float* __restrict__ Zp,
    float* __restrict__ out) {
  const int idx = blockIdx.x * 256 + threadIdx.x;   // float4 index
  const int i = idx >> 6;                           // row (256 feat = 64 f4)
  float z = 0.f;
  #pragma unroll
  for (int y = 0; y < 8; ++y) z += Zp[y * 8192 + i];
  float4v n = {0.f, 0.f, 0.f, 0.f};
  #pragma unroll
  for (int y = 0; y < 8; ++y) {
    float4v v = ((const float4v*)Np)[(size_t)y * 524288 + idx];
    #pragma unroll
    for (int e = 0; e < 4; ++e) n[e] += v[e];
  }
  const float rz = 1.0f / z;
  float4v o;
  #pragma unroll
  for (int e = 0; e < 4; ++e) {
    float v = n[e] * rz;
    o[e] = (v > 0.f) ? v : expm1f(v);
  }
  ((float4v*)out)[idx] = o;
}

// ---------------------------------------------------------------------------
extern "C" void kernel_launch(void* const* d_in, const int* in_sizes, int n_in,
                              void* d_out, int out_size, void* d_ws, size_t ws_size,
                              hipStream_t stream) {
  const int*   adj = (const int*)d_in[0];
  const float* x   = (const float*)d_in[1];
  const float* w   = (const float*)d_in[2];
  const float* a   = (const float*)d_in[3];
  float* out = (float*)d_out;

  // ws layout (~80 MiB of ~1 GiB). hTf (8 MiB f32) lives in d_out
  // transiently; k_out rewrites d_out entirely each call.
  char* ws = (char*)d_ws;
  short*  hT   = (short*)(ws + 0);          //  4 MiB bf16 h^T [256][8192]
  float*  t1p  = (float*)(ws + 4194304);    // 64 KiB
  float*  t2p  = (float*)(ws + 4259840);    // 64 KiB
  float2* e1f1 = (float2*)(ws + 4325376);   // 64 KiB
  float2* ef2  = (float2*)(ws + 4390912);   // 64 KiB
  float*  Zp   = (float*)(ws + 4456448);    // 256 KiB (8 x 8192)
  float*  Np   = (float*)(ws + 16777216);   // 64 MiB (8 x 8192 x 256)
  float*  hTf  = (float*)d_out;             //  8 MiB f32 h^T (transient)

  k_hgemm  <<<128, 256, 0, stream>>>(x, w, hT, hTf);
  k_scores1<<<dim3(32, 2), 256, 0, stream>>>(hTf, a, t1p, t2p);
  k_scores2<<<32, 256, 0, stream>>>(t1p, t2p, e1f1, ef2);
  k_gat    <<<dim3(64, 8), 512, 0, stream>>>(adj, hT, e1f1, ef2, Np, Zp);
  k_out    <<<2048, 256, 0, stream>>>(Np, Zp, out);
}

// Round 14
// 104.377 us; speedup vs baseline: 1.7086x; 1.7086x over previous
//
#include <hip/hip_runtime.h>

typedef short  short8  __attribute__((ext_vector_type(8)));
typedef short  short4v __attribute__((ext_vector_type(4)));
typedef float  float4v __attribute__((ext_vector_type(4)));
typedef int    int4v   __attribute__((ext_vector_type(4)));
typedef int    int2v   __attribute__((ext_vector_type(2)));

#define LOG2E 1.4426950408889634f

static __device__ __forceinline__ short f2bf(float f) {
  unsigned u = __builtin_bit_cast(unsigned, f);
  u = (u + 0x7fffu + ((u >> 16) & 1u)) >> 16;   // RNE
  return (short)u;
}
static __device__ __forceinline__ float bf2f(short s) {
  return __builtin_bit_cast(float, ((unsigned)(unsigned short)s) << 16);
}

typedef __attribute__((address_space(3))) char  as3c;
typedef __attribute__((address_space(1))) char  as1c;
static __device__ __forceinline__ void dma16(const void* g, void* l) {
  __builtin_amdgcn_global_load_lds((const as1c*)g, (as3c*)l, 16, 0, 0);
}

// ---------------------------------------------------------------------------
// Kernel 1: h = x @ w.T  (8192x256, K=256), hi/lo bf16-split MFMA for ~f32
// accuracy. BM=32 -> 256 blocks (full chip). Writes hT bf16 [256][8192] and
// — fused — the score vectors s1 = h@a1, s2 = h@a2 (block owns full rows,
// so the reduction closes in-block via LDS). hTf/f32 scratch eliminated.
// ---------------------------------------------------------------------------
__global__ __launch_bounds__(256) void k_hgemm(
    const float* __restrict__ x, const float* __restrict__ w,
    const float* __restrict__ a, short* __restrict__ hT,
    float* __restrict__ s1, float* __restrict__ s2) {
  __shared__ float zl1[2048], zl2[2048];      // 32 rows x 64 partials
  const int I0   = blockIdx.x * 32;
  const int tid  = threadIdx.x;
  const int lane = tid & 63;
  const int wn   = tid >> 6;               // 4 waves split N (cols)
  const int lrow = lane & 15;
  const int lk8  = (lane >> 4) << 3;

  float a1c[4], a2c[4];
  #pragma unroll
  for (int ni = 0; ni < 4; ++ni) {
    const int col = wn * 64 + ni * 16 + lrow;
    a1c[ni] = a[col];
    a2c[ni] = a[256 + col];
  }

  float4v zero4 = {0.f, 0.f, 0.f, 0.f};
  float4v acc[2][4];
  #pragma unroll
  for (int mi = 0; mi < 2; ++mi)
    #pragma unroll
    for (int ni = 0; ni < 4; ++ni) acc[mi][ni] = zero4;

  for (int k0 = 0; k0 < 256; k0 += 32) {
    short8 ah[2], al[2], bh[4], bl[4];
    #pragma unroll
    for (int mi = 0; mi < 2; ++mi) {
      const float* xp = x + (size_t)(I0 + mi * 16 + lrow) * 256 + k0 + lk8;
      float4v va = *(const float4v*)xp;
      float4v vb = *(const float4v*)(xp + 4);
      #pragma unroll
      for (int e = 0; e < 4; ++e) {
        short h = f2bf(va[e]); ah[mi][e] = h;     al[mi][e]     = f2bf(va[e] - bf2f(h));
        h = f2bf(vb[e]);       ah[mi][4 + e] = h; al[mi][4 + e] = f2bf(vb[e] - bf2f(h));
      }
    }
    #pragma unroll
    for (int ni = 0; ni < 4; ++ni) {
      const float* wp = w + (size_t)(wn * 64 + ni * 16 + lrow) * 256 + k0 + lk8;
      float4v va = *(const float4v*)wp;
      float4v vb = *(const float4v*)(wp + 4);
      #pragma unroll
      for (int e = 0; e < 4; ++e) {
        short h = f2bf(va[e]); bh[ni][e] = h;     bl[ni][e]     = f2bf(va[e] - bf2f(h));
        h = f2bf(vb[e]);       bh[ni][4 + e] = h; bl[ni][4 + e] = f2bf(vb[e] - bf2f(h));
      }
    }
    #pragma unroll
    for (int mi = 0; mi < 2; ++mi)
      #pragma unroll
      for (int ni = 0; ni < 4; ++ni) {
        acc[mi][ni] = __builtin_amdgcn_mfma_f32_16x16x32_bf16(al[mi], bh[ni], acc[mi][ni], 0, 0, 0);
        acc[mi][ni] = __builtin_amdgcn_mfma_f32_16x16x32_bf16(ah[mi], bl[ni], acc[mi][ni], 0, 0, 0);
        acc[mi][ni] = __builtin_amdgcn_mfma_f32_16x16x32_bf16(ah[mi], bh[ni], acc[mi][ni], 0, 0, 0);
      }
  }

  const int r0 = (lane >> 4) << 2;   // C/D: col=lane&15, row=(lane>>4)*4+reg
  // hT store + score partials
  #pragma unroll
  for (int mi = 0; mi < 2; ++mi) {
    #pragma unroll
    for (int ni = 0; ni < 4; ++ni) {
      const int c   = wn * 64 + ni * 16 + lrow;
      const int row = I0 + mi * 16 + r0;
      float4v v = acc[mi][ni];
      short4v sv;
      #pragma unroll
      for (int r = 0; r < 4; ++r) sv[r] = f2bf(v[r]);
      *(short4v*)(hT + (size_t)c * 8192 + row) = sv;
    }
    #pragma unroll
    for (int r = 0; r < 4; ++r) {
      const int srow = mi * 16 + r0 + r;
      float p1 = 0.f, p2 = 0.f;
      #pragma unroll
      for (int ni = 0; ni < 4; ++ni) {
        p1 = fmaf(acc[mi][ni][r], a1c[ni], p1);
        p2 = fmaf(acc[mi][ni][r], a2c[ni], p2);
      }
      const int gcol = wn * 16 + lrow;
      zl1[srow * 64 + gcol] = p1;
      zl2[srow * 64 + gcol] = p2;
    }
  }
  __syncthreads();
  if (tid < 32) {
    float v1 = 0.f, v2 = 0.f;
    #pragma unroll
    for (int g = 0; g < 64; ++g) {
      const int gg = (g + tid) & 63;       // rotate to avoid bank conflicts
      v1 += zl1[tid * 64 + gg];
      v2 += zl2[tid * 64 + gg];
    }
    s1[I0 + tid] = v1;
    s2[I0 + tid] = v2;
  }
}

// ---------------------------------------------------------------------------
// Kernel 2: emit exp2 tables from s1,s2:
//   e1f1[i] = {exp2(t1), exp2(0.2 t1)},  ef2[j] = {exp2(t2), exp2(0.2 t2)}
// so W = adj ? max(e1*e2, f1*f2) : 1  (exp2 of leaky-relu separable via
// monotonicity — no per-element transcendental in k_gat).
// ---------------------------------------------------------------------------
__global__ __launch_bounds__(256) void k_scores2(
    const float* __restrict__ s1, const float* __restrict__ s2,
    float2* __restrict__ e1f1, float2* __restrict__ ef2) {
  const int i = blockIdx.x * 256 + threadIdx.x;
  const float t1 = LOG2E * s1[i];
  const float t2 = LOG2E * s2[i];
  e1f1[i] = make_float2(exp2f(t1), exp2f(0.2f * t1));
  ef2[i]  = make_float2(exp2f(t2), exp2f(0.2f * t2));
}

// ---------------------------------------------------------------------------
// Kernel 4: fused GAT GEMM — r12's counted-vmcnt pipeline VERBATIM (proven
// 126 µs total / ~98 µs k_gat), plus an XCD-aware block remap: linear id
// bid = by*64+bx round-robins over XCDs, so remapping by = bid&3 makes all
// blocks on one XCD share ONE j-window -> their 1 MB hT slice stays
// L2-resident (was: 4 windows cycling the full 4 MB L2). Schedule, LDS
// layout, vmcnt protocol, and staging identical to r12.
// ---------------------------------------------------------------------------
__global__ __launch_bounds__(512) void k_gat(
    const int* __restrict__ adj, const short* __restrict__ hT,
    const float2* __restrict__ e1f1, const float2* __restrict__ ef2,
    float* __restrict__ Np, float* __restrict__ Zp) {
  __shared__ __align__(16) char Wt[2][17408];   // 128 rows x 136B (64j bf16 + 8B pad)
  __shared__ __align__(16) char Hb[2][32768];   // 256 rows x 128B, linear, src-swz
  __shared__ __align__(16) char Elds[16384];    // ef2 slab: 2048 x {e,f} f32

  const int tid = threadIdx.x, lane = tid & 63, wave = tid >> 6;
  const int wm = wave >> 2, wn = wave & 3;
  const int lrow = lane & 15, lk16 = (lane >> 4) << 4;
  // XCD remap: same-XCD blocks (bid mod 8) share by -> shared j-window in L2
  const int bid = blockIdx.y * 64 + blockIdx.x;
  const int bx = bid >> 2, by = bid & 3;
  const int I0 = bx * 128;
  const int j0 = by * 2048;

  // --- W staging map: thread -> rows ar+32p (p=0..3), 4-j chunk aj
  const int ar = tid >> 4, aj = tid & 15;
  const int* agp = adj + (size_t)(I0 + ar) * 8192 + j0 + aj * 4;
  float e1p[4], f1p[4];
  #pragma unroll
  for (int p = 0; p < 4; ++p) {
    float2 v = e1f1[I0 + p * 32 + ar];
    e1p[p] = v.x; f1p[p] = v.y;
  }
  const int wwo = ar * 136 + aj * 8;            // + p*4352, + buf

  // --- H DMA: wave -> rows wave*32..+31; lane l -> row +(l>>3),
  //     global chunk (l&7)^(l>>3) (pre-swizzle; LDS stays linear)
  const int l8 = lane >> 3, l7 = lane & 7;
  const short* hdma = hT + (size_t)(wave * 32 + l8) * 8192 + j0 + (l7 ^ l8) * 8;
  const int hlo = wave * 4096;                  // + q*1024, + buf

  // --- frag-read bases
  const int ardo = (wm * 64 + lrow) * 136 + lk16;      // + mi*2176 + kk*64
  const int brdo = (wn * 64 + lrow) * 128;             // + ni*2048 + (c0 ^ kk<<6)
  const int c0   = ((lane >> 4) ^ (lrow & 7)) << 4;

  float4v zero4 = {0.f, 0.f, 0.f, 0.f};
  float4v acc[4][4];
  #pragma unroll
  for (int mi = 0; mi < 4; ++mi)
    #pragma unroll
    for (int ni = 0; ni < 4; ++ni) acc[mi][ni] = zero4;
  float zacc[4] = {0.f, 0.f, 0.f, 0.f};
  int4v ga[4];

  // W-compute for tile T from ga + Elds, writes to DST (Wt buffer base)
#define WCOMP(T, DST)                                                         \
  { const float4v ge0 = *(const float4v*)(Elds + (T) * 512 + aj * 32);        \
    const float4v ge1 = *(const float4v*)(Elds + (T) * 512 + aj * 32 + 16);   \
    _Pragma("unroll")                                                         \
    for (int p = 0; p < 4; ++p) {                                             \
      float w0 = ga[p][0] ? fmaxf(e1p[p] * ge0[0], f1p[p] * ge0[1]) : 1.0f;   \
      float w1 = ga[p][1] ? fmaxf(e1p[p] * ge0[2], f1p[p] * ge0[3]) : 1.0f;   \
      float w2 = ga[p][2] ? fmaxf(e1p[p] * ge1[0], f1p[p] * ge1[1]) : 1.0f;   \
      float w3 = ga[p][3] ? fmaxf(e1p[p] * ge1[2], f1p[p] * ge1[3]) : 1.0f;   \
      zacc[p] += (w0 + w1) + (w2 + w3);                                       \
      int2v pw;                                                               \
      asm("v_cvt_pk_bf16_f32 %0, %1, %2" : "=v"(pw[0]) : "v"(w0), "v"(w1));   \
      asm("v_cvt_pk_bf16_f32 %0, %1, %2" : "=v"(pw[1]) : "v"(w2), "v"(w3));   \
      *(int2v*)((DST) + wwo + p * 4352) = pw;                                 \
    } }

  // --- prologue: ef table -> LDS; tile-0 staging; counted-wait barrier
  {
    const char* esrc = (const char*)(ef2 + j0);
    *(float4v*)(Elds + tid * 32)      = *(const float4v*)(esrc + tid * 32);
    *(float4v*)(Elds + tid * 32 + 16) = *(const float4v*)(esrc + tid * 32 + 16);
  }
  __syncthreads();                              // Elds visible
  #pragma unroll
  for (int p = 0; p < 4; ++p)
    ga[p] = __builtin_nontemporal_load((const int4v*)(agp + (size_t)p * 262144));
  __builtin_amdgcn_sched_barrier(0);            // pin: adj0 issued first
  #pragma unroll
  for (int q = 0; q < 4; ++q)
    dma16(hdma + q * 65536, Hb[0] + hlo + q * 1024);
  __builtin_amdgcn_sched_barrier(0);            // pin: DMAs before adj1
  WCOMP(0, Wt[0]);
  #pragma unroll
  for (int p = 0; p < 4; ++p)
    ga[p] = __builtin_nontemporal_load((const int4v*)(agp + (size_t)p * 262144 + 64));
  __builtin_amdgcn_sched_barrier(0);            // pin: adj1 after DMAs
  asm volatile("s_waitcnt vmcnt(4) lgkmcnt(0)" ::: "memory");
  __builtin_amdgcn_s_barrier();
  __builtin_amdgcn_sched_barrier(0);

  #pragma unroll 2
  for (int s = 0; s < 32; ++s) {
    const int cur = s & 1, nx = cur ^ 1;
    // P1: DMA H(s+1) into Hb[nx]
    if (s < 31) {
      const int so = (s + 1) * 64;              // shorts
      #pragma unroll
      for (int q = 0; q < 4; ++q)
        dma16(hdma + so + q * 65536, Hb[nx] + hlo + q * 1024);
    }
    __builtin_amdgcn_sched_barrier(0);          // pin: DMA group issued here
    // P2: kk=0 frags + 16 MFMA
    short8 af[4], bf[4];
    #pragma unroll
    for (int mi = 0; mi < 4; ++mi) af[mi] = *(const short8*)(Wt[cur] + ardo + mi * 2176);
    #pragma unroll
    for (int ni = 0; ni < 4; ++ni) bf[ni] = *(const short8*)(Hb[cur] + brdo + ni * 2048 + c0);
    #pragma unroll
    for (int mi = 0; mi < 4; ++mi)
      #pragma unroll
      for (int ni = 0; ni < 4; ++ni)
        acc[mi][ni] = __builtin_amdgcn_mfma_f32_16x16x32_bf16(af[mi], bf[ni], acc[mi][ni], 0, 0, 0);
    // P3: W-compute(s+1) -> Wt[nx] (VALU covers the DMA in flight)
    if (s < 31) WCOMP(s + 1, Wt[nx]);
    // P4: issue adj — EVERY s<31 (clamped) so each barrier has exactly 4
    //     adj ops in flight behind the 4 DMAs (vmcnt(4) drains DMAs only)
    if (s < 31) {
      const int sp = (s + 2 < 32) ? s + 2 : 31;
      const int so = sp * 64;                   // ints
      #pragma unroll
      for (int p = 0; p < 4; ++p)
        ga[p] = __builtin_nontemporal_load((const int4v*)(agp + (size_t)p * 262144 + so));
    }
    __builtin_amdgcn_sched_barrier(0);          // pin: adj group after DMAs
    // P5: kk=1 frags + 16 MFMA
    #pragma unroll
    for (int mi = 0; mi < 4; ++mi) af[mi] = *(const short8*)(Wt[cur] + ardo + mi * 2176 + 64);
    #pragma unroll
    for (int ni = 0; ni < 4; ++ni) bf[ni] = *(const short8*)(Hb[cur] + brdo + ni * 2048 + (c0 ^ 64));
    #pragma unroll
    for (int mi = 0; mi < 4; ++mi)
      #pragma unroll
      for (int ni = 0; ni < 4; ++ni)
        acc[mi][ni] = __builtin_amdgcn_mfma_f32_16x16x32_bf16(af[mi], bf[ni], acc[mi][ni], 0, 0, 0);
    // P6: counted drain (DMAs only; adj loads stay in flight) + raw barrier
    if (s < 31) {
      asm volatile("s_waitcnt vmcnt(4) lgkmcnt(0)" ::: "memory");
      __builtin_amdgcn_s_barrier();
      __builtin_amdgcn_sched_barrier(0);
    }
  }
#undef WCOMP

  // Z reduce: per-thread partials -> LDS (alias over Elds) -> 1/row
  __syncthreads();
  float* zl = (float*)Elds;
  #pragma unroll
  for (int p = 0; p < 4; ++p) zl[(ar + p * 32) * 16 + aj] = zacc[p];
  __syncthreads();
  if (tid < 128) {
    float z = 0.f;
    #pragma unroll
    for (int g = 0; g < 16; ++g) z += zl[tid * 16 + g];
    Zp[(size_t)by * 8192 + I0 + tid] = z;
  }

  // N partial store (direct, no atomics)
  float* Npb = Np + (size_t)by * 2097152;
  const int r0 = (lane >> 4) << 2;
  #pragma unroll
  for (int mi = 0; mi < 4; ++mi) {
    const int rowb = I0 + wm * 64 + mi * 16 + r0;
    #pragma unroll
    for (int ni = 0; ni < 4; ++ni) {
      const int col = wn * 64 + ni * 16 + lrow;
      #pragma unroll
      for (int r = 0; r < 4; ++r)
        Npb[(size_t)(rowb + r) * 256 + col] = acc[mi][ni][r];
    }
  }
}

// ---------------------------------------------------------------------------
// Kernel 5: out = elu( (sum_y Np) / (sum_y Zp) )   (4 split-K slabs)
// ---------------------------------------------------------------------------
__global__ __launch_bounds__(256) void k_out(
    const float* __restrict__ Np, const float* __restrict__ Zp,
    float* __restrict__ out) {
  const int idx = blockIdx.x * 256 + threadIdx.x;   // float4 index
  const int i = idx >> 6;                           // row (256 feat = 64 f4)
  float z = 0.f;
  #pragma unroll
  for (int y = 0; y < 4; ++y) z += Zp[y * 8192 + i];
  float4v n = {0.f, 0.f, 0.f, 0.f};
  #pragma unroll
  for (int y = 0; y < 4; ++y) {
    float4v v = ((const float4v*)Np)[(size_t)y * 524288 + idx];
    #pragma unroll
    for (int e = 0; e < 4; ++e) n[e] += v[e];
  }
  const float rz = 1.0f / z;
  float4v o;
  #pragma unroll
  for (int e = 0; e < 4; ++e) {
    float v = n[e] * rz;
    o[e] = (v > 0.f) ? v : expm1f(v);
  }
  ((float4v*)out)[idx] = o;
}

// ---------------------------------------------------------------------------
extern "C" void kernel_launch(void* const* d_in, const int* in_sizes, int n_in,
                              void* d_out, int out_size, void* d_ws, size_t ws_size,
                              hipStream_t stream) {
  const int*   adj = (const int*)d_in[0];
  const float* x   = (const float*)d_in[1];
  const float* w   = (const float*)d_in[2];
  const float* a   = (const float*)d_in[3];
  float* out = (float*)d_out;

  // ws layout (~48 MiB of ~1 GiB). d_out is written only by k_out.
  char* ws = (char*)d_ws;
  short*  hT   = (short*)(ws + 0);          //  4 MiB bf16 h^T [256][8192]
  float*  s1   = (float*)(ws + 4194304);    // 32 KiB
  float*  s2   = (float*)(ws + 4259840);    // 32 KiB
  float2* e1f1 = (float2*)(ws + 4325376);   // 64 KiB
  float2* ef2  = (float2*)(ws + 4390912);   // 64 KiB
  float*  Zp   = (float*)(ws + 4456448);    // 128 KiB (4 x 8192)
  float*  Np   = (float*)(ws + 16777216);   // 32 MiB (4 x 8192 x 256)

  k_hgemm  <<<256, 256, 0, stream>>>(x, w, a, hT, s1, s2);
  k_scores2<<<32, 256, 0, stream>>>(s1, s2, e1f1, ef2);
  k_gat    <<<dim3(64, 4), 512, 0, stream>>>(adj, hT, e1f1, ef2, Np, Zp);
  k_out    <<<2048, 256, 0, stream>>>(Np, Zp, out);
}